// Round 5
// baseline (297.263 us; speedup 1.0000x reference)
//
#include <hip/hip_runtime.h>

// Varifold loss, round 5: MFMA (16x16x32 f16, exact hi/lo split) for both
// bilinear forms; VALU keeps only exp2 + d^2 + accumulate.
//
// t_ij  = cq_i + cq_j + TG*<C_i,C_j>   (TG = 2*gamma*log2e, cq = -gamma*log2e*|C|^2)
//   K=16: [TGh(3),TGl(3),TGh(3),TGl(3),cqh,cql,1,1] . [Ch,Ch,Cl,Cl,1,1,cqh,cql]
// d_ij  = <m_i,m_j>, m = Nn*sqrt(L)
//   K=12: [mh,ml,mh,ml] . [mh,mh,ml,ml]   (exact (mh+ml).(mh+ml))
// pair term = exp2(t) * d^2, weights/signs uniform per (panel, j-tile).

#define NVERT 5023
#define NFACE 9976
#define BATCH 4
#define HALFP 9984            // per-mesh faces padded to x16
#define NTP   (2 * HALFP)     // 19968 faces per batch
#define NJT   1248            // j-tiles of 16
#define NPAN  156             // i-panels of 128
#define SPLITS 4              // j-chunks per panel pair

#define RECH 64               // halfs per face record
#define OTA 0
#define ODA 16
#define OTB 32
#define ODB 48

constexpr float GAMMA = 1.0f / (0.03f * 0.03f);
constexpr float LOG2E = 1.4426950408889634f;
constexpr float EPSV  = 1e-12f;

typedef _Float16 half8_t __attribute__((ext_vector_type(8)));
typedef float    f32x4   __attribute__((ext_vector_type(4)));

__global__ __launch_bounds__(256)
void face_quant_kernel(const float* __restrict__ pred,
                       const float* __restrict__ targ,
                       const int*   __restrict__ faces,
                       _Float16*    __restrict__ fd,
                       float*       __restrict__ out) {
    int idx = blockIdx.x * 256 + threadIdx.x;
    if (idx == 0) out[0] = 0.0f;
    const int total = BATCH * NTP;
    if (idx >= total) return;

    int b     = idx / NTP;
    int s     = idx - b * NTP;
    int which = (s >= HALFP) ? 1 : 0;
    int f     = s - which * HALFP;

    _Float16* rec = fd + (size_t)idx * RECH;

    if (f >= NFACE) {
        half8_t z = {};
        #pragma unroll
        for (int k = 0; k < 8; ++k) *(half8_t*)(rec + k * 8) = z;
        return;
    }

    const float* V = (which ? targ : pred) + (size_t)b * NVERT * 3;
    int i0 = faces[f * 3 + 0];
    int i1 = faces[f * 3 + 1];
    int i2 = faces[f * 3 + 2];

    float v0x = V[i0*3+0], v0y = V[i0*3+1], v0z = V[i0*3+2];
    float v1x = V[i1*3+0], v1y = V[i1*3+1], v1z = V[i1*3+2];
    float v2x = V[i2*3+0], v2y = V[i2*3+1], v2z = V[i2*3+2];

    const float third = 1.0f / 3.0f;
    float cx = (v0x + v1x + v2x) * third;
    float cy = (v0y + v1y + v2y) * third;
    float cz = (v0z + v1z + v2z) * third;

    float e1x = v1x - v0x, e1y = v1y - v0y, e1z = v1z - v0z;
    float e2x = v2x - v0x, e2y = v2y - v0y, e2z = v2z - v0z;

    float nx = 0.5f * (e1y * e2z - e1z * e2y);
    float ny = 0.5f * (e1z * e2x - e1x * e2z);
    float nz = 0.5f * (e1x * e2y - e1y * e2x);

    float L   = sqrtf(nx*nx + ny*ny + nz*nz);
    float inv = 1.0f / fmaxf(L, EPSV);
    float sc  = inv * sqrtf(L);            // m = Nn*sqrt(L)
    float mx = nx * sc, my = ny * sc, mz = nz * sc;

    const float TG = 2.0f * GAMMA * LOG2E;
    float tgx = TG * cx, tgy = TG * cy, tgz = TG * cz;
    float cq  = -GAMMA * LOG2E * (cx*cx + cy*cy + cz*cz);

    // hi/lo f16 splits
    _Float16 TGxh = (_Float16)tgx; _Float16 TGxl = (_Float16)(tgx - (float)TGxh);
    _Float16 TGyh = (_Float16)tgy; _Float16 TGyl = (_Float16)(tgy - (float)TGyh);
    _Float16 TGzh = (_Float16)tgz; _Float16 TGzl = (_Float16)(tgz - (float)TGzh);
    _Float16 Cxh  = (_Float16)cx;  _Float16 Cxl  = (_Float16)(cx  - (float)Cxh);
    _Float16 Cyh  = (_Float16)cy;  _Float16 Cyl  = (_Float16)(cy  - (float)Cyh);
    _Float16 Czh  = (_Float16)cz;  _Float16 Czl  = (_Float16)(cz  - (float)Czh);
    _Float16 cqh  = (_Float16)cq;  _Float16 cql  = (_Float16)(cq  - (float)cqh);
    _Float16 mxh  = (_Float16)mx;  _Float16 mxl  = (_Float16)(mx  - (float)mxh);
    _Float16 myh  = (_Float16)my;  _Float16 myl  = (_Float16)(my  - (float)myh);
    _Float16 mzh  = (_Float16)mz;  _Float16 mzl  = (_Float16)(mz  - (float)mzh);
    _Float16 one  = (_Float16)1.0f;
    _Float16 zz   = (_Float16)0.0f;

    half8_t ta0 = {TGxh, TGyh, TGzh, TGxl, TGyl, TGzl, TGxh, TGyh};
    half8_t ta1 = {TGzh, TGxl, TGyl, TGzl, cqh,  cql,  one,  one };
    half8_t da0 = {mxh,  myh,  mzh,  mxl,  myl,  mzl,  mxh,  myh };
    half8_t da1 = {mzh,  mxl,  myl,  mzl,  zz,   zz,   zz,   zz  };
    half8_t tb0 = {Cxh,  Cyh,  Czh,  Cxh,  Cyh,  Czh,  Cxl,  Cyl };
    half8_t tb1 = {Czl,  Cxl,  Cyl,  Czl,  one,  one,  cqh,  cql };
    half8_t db0 = {mxh,  myh,  mzh,  mxh,  myh,  mzh,  mxl,  myl };
    half8_t db1 = {mzl,  mxl,  myl,  mzl,  zz,   zz,   zz,   zz  };

    *(half8_t*)(rec + OTA + 0) = ta0;  *(half8_t*)(rec + OTA + 8) = ta1;
    *(half8_t*)(rec + ODA + 0) = da0;  *(half8_t*)(rec + ODA + 8) = da1;
    *(half8_t*)(rec + OTB + 0) = tb0;  *(half8_t*)(rec + OTB + 8) = tb1;
    *(half8_t*)(rec + ODB + 0) = db0;  *(half8_t*)(rec + ODB + 8) = db1;
}

__device__ __forceinline__ half8_t ld_frag(const _Float16* p) {
    return *(const half8_t*)p;
}

__global__ __launch_bounds__(256)
void pair_sum_kernel(const _Float16* __restrict__ fd,
                     float*          __restrict__ out) {
    const int b       = blockIdx.z;
    const int pairIdx = blockIdx.x / SPLITS;
    const int s       = blockIdx.x % SPLITS;

    const _Float16* base = fd + (size_t)b * NTP * RECH;

    const int lane = threadIdx.x & 63;
    const int w    = threadIdx.x >> 6;
    const int q    = lane >> 4;       // quad: k-range q*8..q*8+7 (q<2 live)
    const int fcol = lane & 15;

    float acc = 0.0f;

    #pragma unroll 1
    for (int half = 0; half < 2; ++half) {
        const int P  = half ? (NPAN - 1 - pairIdx) : pairIdx;
        const int jb = P * 8;                     // band start (j-tiles)
        const float si = (P < NPAN / 2) ? 1.0f : -1.0f;

        // A-frags for this wave's two i-tiles (rows P*128+w*16 and +64)
        half8_t aT0 = {}, aD0 = {}, aT1 = {}, aD1 = {};
        {
            const _Float16* r0 = base + (size_t)(P * 128 + w * 16 + fcol) * RECH;
            const _Float16* r1 = r0 + (size_t)64 * RECH;
            if (q < 2) {
                aT0 = ld_frag(r0 + OTA + q * 8);
                aD0 = ld_frag(r0 + ODA + q * 8);
                aT1 = ld_frag(r1 + OTA + q * 8);
                aD1 = ld_frag(r1 + ODA + q * 8);
            }
        }

        int tj = jb + s;
        half8_t bT = {}, bD = {};
        if (tj < NJT && q < 2) {
            const _Float16* jr = base + (size_t)(tj * 16 + fcol) * RECH;
            bT = ld_frag(jr + OTB + q * 8);
            bD = ld_frag(jr + ODB + q * 8);
        }

        while (tj < NJT) {
            const int tjn = tj + SPLITS;
            half8_t nT = {}, nD = {};
            if (tjn < NJT && q < 2) {
                const _Float16* jr = base + (size_t)(tjn * 16 + fcol) * RECH;
                nT = ld_frag(jr + OTB + q * 8);
                nD = ld_frag(jr + ODB + q * 8);
            }

            f32x4 z = {0.f, 0.f, 0.f, 0.f};
            f32x4 cT0 = __builtin_amdgcn_mfma_f32_16x16x32_f16(aT0, bT, z, 0, 0, 0);
            f32x4 cD0 = __builtin_amdgcn_mfma_f32_16x16x32_f16(aD0, bD, z, 0, 0, 0);
            f32x4 cT1 = __builtin_amdgcn_mfma_f32_16x16x32_f16(aT1, bT, z, 0, 0, 0);
            f32x4 cD1 = __builtin_amdgcn_mfma_f32_16x16x32_f16(aD1, bD, z, 0, 0, 0);

            float ts = 0.0f;
            #pragma unroll
            for (int r = 0; r < 4; ++r) {
                float e0 = __builtin_amdgcn_exp2f(cT0[r]);
                float d0 = cD0[r];
                ts = fmaf(e0, d0 * d0, ts);
                float e1 = __builtin_amdgcn_exp2f(cT1[r]);
                float d1 = cD1[r];
                ts = fmaf(e1, d1 * d1, ts);
            }

            float sj  = (tj < NJT / 2) ? 1.0f : -1.0f;
            float wgt = (tj < jb + 8) ? 1.0f : 2.0f;
            acc = fmaf(si * sj * wgt * (1.0f / BATCH), ts, acc);

            bT = nT; bD = nD; tj = tjn;
        }
    }

    #pragma unroll
    for (int off = 32; off > 0; off >>= 1)
        acc += __shfl_down(acc, off, 64);

    __shared__ float wsum[4];
    if (lane == 0) wsum[w] = acc;
    __syncthreads();
    if (threadIdx.x == 0)
        atomicAdd(out, wsum[0] + wsum[1] + wsum[2] + wsum[3]);
}

extern "C" void kernel_launch(void* const* d_in, const int* in_sizes, int n_in,
                              void* d_out, int out_size, void* d_ws, size_t ws_size,
                              hipStream_t stream) {
    const float* pred  = (const float*)d_in[0];
    const float* targ  = (const float*)d_in[1];
    const int*   faces = (const int*)d_in[2];
    float*       out   = (float*)d_out;
    _Float16*    fd    = (_Float16*)d_ws;   // BATCH*NTP*128 B = 10.2 MB

    const int totalSlots = BATCH * NTP;
    face_quant_kernel<<<(totalSlots + 255) / 256, 256, 0, stream>>>(
        pred, targ, faces, fd, out);

    dim3 grid((NPAN / 2) * SPLITS, 1, BATCH);   // 312 x 1 x 4
    pair_sum_kernel<<<grid, 256, 0, stream>>>(fd, out);
}